// Round 1
// baseline (1071.051 us; speedup 1.0000x reference)
//
#include <hip/hip_runtime.h>
#include <cstdint>
#include <cstddef>

// ---------------------------------------------------------------------------
// OppoModelNet: GNN forward
//   encoder (256->512->256) -> LSTM step (256) -> nf (128)
//   edge MLP (256->256->128) + segment_sum(dst) -> node MLP (256->256->128)
//   readout (128->256->8).  Outputs: logits [N,8], h1 [N,256], c1 [N,256]
// All GEMMs: bf16 MFMA 16x16x32, fp32 accumulate.
// ---------------------------------------------------------------------------

#define NN 65536      // nodes
#define NE 524288     // edges

typedef __bf16 bf16x8 __attribute__((ext_vector_type(8)));
typedef float  f32x4  __attribute__((ext_vector_type(4)));

__device__ __forceinline__ float bf2f(unsigned short u){
  union { unsigned int i; float f; } v; v.i = ((unsigned int)u) << 16; return v.f;
}
__device__ __forceinline__ unsigned short f2b(float f){
  union { float f; unsigned int i; } v; v.f = f;
  unsigned int r = v.i + 0x7FFFu + ((v.i >> 16) & 1u);
  return (unsigned short)(r >> 16);
}
__device__ __forceinline__ float sigm(float x){ return 1.f/(1.f+__expf(-x)); }

// Fragment-ordered 64x32 LDS tile: element (row,k) at
//   idx = (row>>4)*512 + ((k>>3)&3)*128 + (row&15)*8 + (k&7)
// -> a wave's ds_read_b128 of its 16x32 subtile is perfectly lane-sequential.

// ---------------------------------------------------------------------------
// batched fp32 -> bf16 conversion (obs, h0, 11 weight matrices)
// ---------------------------------------------------------------------------
struct ConvArgs {
  const float* s[14];
  unsigned short* d[14];
  int n4[14];
  int cnt;
};

__global__ __launch_bounds__(256) void convert_kernel(ConvArgs a){
  int stride = gridDim.x * blockDim.x;
  int gid = blockIdx.x * blockDim.x + threadIdx.x;
  for (int seg = 0; seg < a.cnt; ++seg){
    const float4* s = (const float4*)a.s[seg];
    ushort4* d = (ushort4*)a.d[seg];
    int n4 = a.n4[seg];
    for (int i = gid; i < n4; i += stride){
      float4 v = s[i];
      ushort4 o; o.x=f2b(v.x); o.y=f2b(v.y); o.z=f2b(v.z); o.w=f2b(v.w);
      d[i] = o;
    }
  }
}

// ---------------------------------------------------------------------------
// generic bf16 GEMM: C[M,Ncols] = act(A[M,K] @ B[Ncols,K]^T + bias), bf16 out
// tile 64x64, BK=32, 256 threads (4 waves m-split), grid (M/64, Ncols/64)
// ---------------------------------------------------------------------------
template<int ACT>
__global__ __launch_bounds__(256) void gemm_kernel(
    const unsigned short* __restrict__ A, int lda,
    const unsigned short* __restrict__ B, int K,     // B is [Ncols][K], ldb=K
    const float* __restrict__ bias,
    unsigned short* __restrict__ C, int ldc)
{
  __shared__ alignas(16) unsigned short As[2048];
  __shared__ alignas(16) unsigned short Bs[2048];
  int t = threadIdx.x, wave = t >> 6, lane = t & 63;
  int m0 = blockIdx.x * 64, n0 = blockIdx.y * 64;

  f32x4 acc[4] = {};
  int row = t >> 2, chunk = t & 3;
  int sidx = ((row >> 4) << 9) + (chunk << 7) + ((row & 15) << 3);
  const unsigned short* Ap = A + (size_t)(m0 + row) * lda + chunk * 8;
  const unsigned short* Bp = B + (size_t)(n0 + row) * K + chunk * 8;

  for (int kt = 0; kt < K; kt += 32){
    __syncthreads();
    *(uint4*)&As[sidx] = *(const uint4*)(Ap + kt);
    *(uint4*)&Bs[sidx] = *(const uint4*)(Bp + kt);
    __syncthreads();
    bf16x8 a = *(const bf16x8*)&As[(wave << 9) + ((lane >> 4) << 7) + ((lane & 15) << 3)];
#pragma unroll
    for (int j = 0; j < 4; ++j){
      bf16x8 b = *(const bf16x8*)&Bs[(j << 9) + ((lane >> 4) << 7) + ((lane & 15) << 3)];
      acc[j] = __builtin_amdgcn_mfma_f32_16x16x32_bf16(a, b, acc[j], 0, 0, 0);
    }
  }

  int coll = lane & 15, rq = lane >> 4;
#pragma unroll
  for (int j = 0; j < 4; ++j){
    int col = n0 + j * 16 + coll;
    float bv = bias[col];
#pragma unroll
    for (int r = 0; r < 4; ++r){
      int rrow = m0 + wave * 16 + rq * 4 + r;
      float v = acc[j][r] + bv;
      if (ACT) v = fmaxf(v, 0.f);
      C[(size_t)rrow * ldc + col] = f2b(v);
    }
  }
}

// ---------------------------------------------------------------------------
// gates = [x|h0] @ [w_ih|w_hh]^T + b ; LSTM elementwise fused in registers.
// Block: 64 nodes x 64 cols-per-gate, all 4 gates concurrently (acc[4][4]).
// grid (N/64, 256/64)
// ---------------------------------------------------------------------------
__global__ __launch_bounds__(256) void gates_lstm_kernel(
    const unsigned short* __restrict__ Xb,   // [N,256] bf16
    const unsigned short* __restrict__ H0b,  // [N,256] bf16
    const unsigned short* __restrict__ Wih,  // [1024][256] bf16
    const unsigned short* __restrict__ Whh,  // [1024][256] bf16
    const float* __restrict__ b_ih, const float* __restrict__ b_hh,
    const float* __restrict__ c0,            // [N,256] fp32
    float* __restrict__ h1o, float* __restrict__ c1o,  // fp32 outputs
    unsigned short* __restrict__ rb)         // relu(h1) bf16 [N,256]
{
  __shared__ alignas(16) unsigned short As[2048];
  __shared__ alignas(16) unsigned short Bs[4][2048];
  int t = threadIdx.x, wave = t >> 6, lane = t & 63;
  int m0 = blockIdx.x * 64, cb = blockIdx.y * 64;

  f32x4 acc[4][4] = {};
  int row = t >> 2, chunk = t & 3;
  int sidx = ((row >> 4) << 9) + (chunk << 7) + ((row & 15) << 3);

  for (int kt = 0; kt < 512; kt += 32){
    const unsigned short* Ap = (kt < 256)
        ? (Xb  + (size_t)(m0 + row) * 256 + kt)
        : (H0b + (size_t)(m0 + row) * 256 + (kt - 256));
    __syncthreads();
    *(uint4*)&As[sidx] = *(const uint4*)(Ap + chunk * 8);
#pragma unroll
    for (int g = 0; g < 4; ++g){
      const unsigned short* Wp = (kt < 256)
          ? (Wih + (size_t)(g * 256 + cb + row) * 256 + kt)
          : (Whh + (size_t)(g * 256 + cb + row) * 256 + (kt - 256));
      *(uint4*)&Bs[g][sidx] = *(const uint4*)(Wp + chunk * 8);
    }
    __syncthreads();
    bf16x8 a = *(const bf16x8*)&As[(wave << 9) + ((lane >> 4) << 7) + ((lane & 15) << 3)];
#pragma unroll
    for (int g = 0; g < 4; ++g){
#pragma unroll
      for (int j = 0; j < 4; ++j){
        bf16x8 b = *(const bf16x8*)&Bs[g][(j << 9) + ((lane >> 4) << 7) + ((lane & 15) << 3)];
        acc[g][j] = __builtin_amdgcn_mfma_f32_16x16x32_bf16(a, b, acc[g][j], 0, 0, 0);
      }
    }
  }

  int coll = lane & 15, rq = lane >> 4;
#pragma unroll
  for (int j = 0; j < 4; ++j){
    int col = cb + j * 16 + coll;          // LSTM feature index, 0..255
    float bi  = b_ih[col]       + b_hh[col];
    float bff = b_ih[256 + col] + b_hh[256 + col];
    float bg  = b_ih[512 + col] + b_hh[512 + col];
    float bo  = b_ih[768 + col] + b_hh[768 + col];
#pragma unroll
    for (int r = 0; r < 4; ++r){
      int node = m0 + wave * 16 + rq * 4 + r;
      size_t off = (size_t)node * 256 + col;
      float iv = sigm(acc[0][j][r] + bi);
      float fv = sigm(acc[1][j][r] + bff);
      float gv = tanhf(acc[2][j][r] + bg);
      float ov = sigm(acc[3][j][r] + bo);
      float cv = fv * c0[off] + iv * gv;
      float hv = ov * tanhf(cv);
      h1o[off] = hv;
      c1o[off] = cv;
      rb[off] = f2b(fmaxf(hv, 0.f));
    }
  }
}

// ---------------------------------------------------------------------------
// edge MLP + scatter: per block 64 edges.
//   einp = [nf[src], nf[dst]] (K=256) -> relu(@we^T+be) (256) -> @we2^T+be2 (128)
//   atomicAdd into agg[dst]
// nf rows live in ninp[:,0:128] with row stride 256.
// ---------------------------------------------------------------------------
__global__ __launch_bounds__(256) void edge_kernel(
    const unsigned short* __restrict__ ninp,  // [N,256] bf16 (cols 0..127 = nf)
    const int* __restrict__ src, const int* __restrict__ dst,
    const unsigned short* __restrict__ Web,   // [256][256] bf16
    const float* __restrict__ be,
    const unsigned short* __restrict__ We2b,  // [128][256] bf16
    const float* __restrict__ be2,
    float* __restrict__ agg)                  // [N,128] fp32
{
  __shared__ alignas(16) unsigned short EH[64 * 256]; // einp, then hidden (frag order)
  __shared__ alignas(16) unsigned short Bs[8192];     // weight staging (16KB)
  __shared__ int ssrc[64], sdst[64];

  int t = threadIdx.x, wave = t >> 6, lane = t & 63;
  int e0 = blockIdx.x * 64;
  if (t < 64){ ssrc[t] = src[e0 + t]; sdst[t] = dst[e0 + t]; }
  __syncthreads();

  // gather einp into EH (fragment order, [8 ktiles][64x32])
  {
    int e = t >> 2, part = t & 3;
    int sn = ssrc[e], dn = sdst[e];
#pragma unroll
    for (int ch = 0; ch < 8; ++ch){
      int k = part * 64 + ch * 8;
      int node = (k < 128) ? sn : dn;
      int col = k & 127;
      uint4 v = *(const uint4*)&ninp[(size_t)node * 256 + col];
      int idx = ((k >> 5) << 11) + ((e >> 4) << 9) + (((k >> 3) & 3) << 7) + ((e & 15) << 3);
      *(uint4*)&EH[idx] = v;
    }
  }

  int brow = t >> 2, bchunk = t & 3;

  // layer 1: hidden[64,256]
  f32x4 acc[16] = {};
  for (int kt = 0; kt < 256; kt += 32){
    __syncthreads();
#pragma unroll
    for (int p = 0; p < 4; ++p){
      int r = p * 64 + brow;
      uint4 v = *(const uint4*)&Web[(size_t)r * 256 + kt + bchunk * 8];
      int idx = ((r >> 4) << 9) + (bchunk << 7) + ((r & 15) << 3);
      *(uint4*)&Bs[idx] = v;
    }
    __syncthreads();
    bf16x8 a = *(const bf16x8*)&EH[((kt >> 5) << 11) + (wave << 9) + ((lane >> 4) << 7) + ((lane & 15) << 3)];
#pragma unroll
    for (int j = 0; j < 16; ++j){
      bf16x8 b = *(const bf16x8*)&Bs[(j << 9) + ((lane >> 4) << 7) + ((lane & 15) << 3)];
      acc[j] = __builtin_amdgcn_mfma_f32_16x16x32_bf16(a, b, acc[j], 0, 0, 0);
    }
  }

  __syncthreads();  // all einp reads done; EH can be overwritten with hidden
  {
    int coll = lane & 15, rq = lane >> 4;
#pragma unroll
    for (int j = 0; j < 16; ++j){
      int col = j * 16 + coll;
      float bv = be[col];
#pragma unroll
      for (int r = 0; r < 4; ++r){
        int row = wave * 16 + rq * 4 + r;
        float v = fmaxf(acc[j][r] + bv, 0.f);
        int idx = ((col >> 5) << 11) + ((row >> 4) << 9) + (((col >> 3) & 3) << 7) + ((row & 15) << 3) + (col & 7);
        EH[idx] = f2b(v);
      }
    }
  }

  // layer 2: ef[64,128]
  f32x4 acc2[8] = {};
  for (int kt = 0; kt < 256; kt += 32){
    __syncthreads();
#pragma unroll
    for (int p = 0; p < 2; ++p){
      int r = p * 64 + brow;
      uint4 v = *(const uint4*)&We2b[(size_t)r * 256 + kt + bchunk * 8];
      int idx = ((r >> 4) << 9) + (bchunk << 7) + ((r & 15) << 3);
      *(uint4*)&Bs[idx] = v;
    }
    __syncthreads();
    bf16x8 a = *(const bf16x8*)&EH[((kt >> 5) << 11) + (wave << 9) + ((lane >> 4) << 7) + ((lane & 15) << 3)];
#pragma unroll
    for (int j = 0; j < 8; ++j){
      bf16x8 b = *(const bf16x8*)&Bs[(j << 9) + ((lane >> 4) << 7) + ((lane & 15) << 3)];
      acc2[j] = __builtin_amdgcn_mfma_f32_16x16x32_bf16(a, b, acc2[j], 0, 0, 0);
    }
  }

  // scatter: atomicAdd into agg[dst]
  {
    int coll = lane & 15, rq = lane >> 4;
#pragma unroll
    for (int j = 0; j < 8; ++j){
      int col = j * 16 + coll;
      float bv = be2[col];
#pragma unroll
      for (int r = 0; r < 4; ++r){
        int erow = wave * 16 + rq * 4 + r;
        int d = sdst[erow];
        atomicAdd(&agg[(size_t)d * 128 + col], acc2[j][r] + bv);
      }
    }
  }
}

// ---------------------------------------------------------------------------
// agg fp32 -> bf16 into ninp cols 128..255
// ---------------------------------------------------------------------------
__global__ __launch_bounds__(256) void aggconv_kernel(
    const float* __restrict__ agg, unsigned short* __restrict__ ninp)
{
  int i = blockIdx.x * blockDim.x + threadIdx.x;  // chunk over N*32
  int n = i >> 5, c = (i & 31) * 4;
  float4 v = *(const float4*)&agg[(size_t)n * 128 + c];
  ushort4 o; o.x=f2b(v.x); o.y=f2b(v.y); o.z=f2b(v.z); o.w=f2b(v.w);
  *(ushort4*)&ninp[(size_t)n * 256 + 128 + c] = o;
}

// ---------------------------------------------------------------------------
// readout layer 2: logits[N,8] = rh[N,256] @ wr2[8,256]^T + br2  (fp32 out)
// ---------------------------------------------------------------------------
__global__ __launch_bounds__(256) void logits_kernel(
    const unsigned short* __restrict__ rh,
    const unsigned short* __restrict__ wr2b,
    const float* __restrict__ br2,
    float* __restrict__ out)
{
  __shared__ alignas(16) unsigned short W[2048];
  int t = threadIdx.x;
  *(uint4*)&W[t * 8] = *(const uint4*)&wr2b[t * 8];
  __syncthreads();
  int node = blockIdx.x * 32 + (t >> 3);
  int o = t & 7;
  const unsigned short* r = rh + (size_t)node * 256;
  float s = br2[o];
#pragma unroll
  for (int k = 0; k < 256; k += 8){
    uint4 av = *(const uint4*)&r[k];
    const unsigned short* ap = (const unsigned short*)&av;
#pragma unroll
    for (int i = 0; i < 8; ++i) s += bf2f(ap[i]) * bf2f(W[o * 256 + k + i]);
  }
  out[(size_t)node * 8 + o] = s;
}

// ---------------------------------------------------------------------------
extern "C" void kernel_launch(void* const* d_in, const int* in_sizes, int n_in,
                              void* d_out, int out_size, void* d_ws, size_t ws_size,
                              hipStream_t stream)
{
  (void)in_sizes; (void)n_in; (void)out_size; (void)ws_size;
  const float* obs = (const float*)d_in[0];
  const float* h0  = (const float*)d_in[1];
  const float* c0  = (const float*)d_in[2];
  const int*   src = (const int*)d_in[3];
  const int*   dst = (const int*)d_in[4];
  const float* w1a = (const float*)d_in[5];
  const float* b1a = (const float*)d_in[6];
  const float* w1b = (const float*)d_in[7];
  const float* b1b = (const float*)d_in[8];
  const float* wih = (const float*)d_in[9];
  const float* bih = (const float*)d_in[10];
  const float* whh = (const float*)d_in[11];
  const float* bhh = (const float*)d_in[12];
  const float* w1  = (const float*)d_in[13];
  const float* b1  = (const float*)d_in[14];
  const float* we  = (const float*)d_in[15];
  const float* be  = (const float*)d_in[16];
  const float* we2 = (const float*)d_in[17];
  const float* be2 = (const float*)d_in[18];
  const float* wn  = (const float*)d_in[19];
  const float* bn  = (const float*)d_in[20];
  const float* wn2 = (const float*)d_in[21];
  const float* bn2 = (const float*)d_in[22];
  const float* wr  = (const float*)d_in[23];
  const float* br  = (const float*)d_in[24];
  const float* wr2 = (const float*)d_in[25];
  const float* br2 = (const float*)d_in[26];

  char* ws = (char*)d_ws;
  typedef unsigned short u16;
  // bf16 weight copies
  u16* w1a_b = (u16*)(ws + 0);
  u16* w1b_b = (u16*)(ws + 262144);
  u16* wih_b = (u16*)(ws + 524288);
  u16* whh_b = (u16*)(ws + 1048576);
  u16* w1_b  = (u16*)(ws + 1572864);
  u16* we_b  = (u16*)(ws + 1638400);
  u16* we2_b = (u16*)(ws + 1769472);
  u16* wn_b  = (u16*)(ws + 1835008);
  u16* wn2_b = (u16*)(ws + 1966080);
  u16* wr_b  = (u16*)(ws + 2031616);
  u16* wr2_b = (u16*)(ws + 2097152);
  // aliased activation regions
  char* RA = ws + 2101248;    // 33.5MB: obs_b -> x_b -> agg(fp32)
  char* RB = ws + 35655680;   // 33.5MB: h0_b -> hidn -> rh
  char* RY = ws + 69210112;   // 67MB:   y1 -> (rb | ninp)
  char* RN = ws + 136318976;  // 16.8MB: nf2

  u16* obs_b = (u16*)RA;
  u16* x_b   = (u16*)RA;
  float* agg = (float*)RA;
  u16* h0_b  = (u16*)RB;
  u16* hidn  = (u16*)RB;
  u16* rh    = (u16*)RB;
  u16* y1    = (u16*)RY;
  u16* rb    = (u16*)RY;
  u16* ninp  = (u16*)(RY + 33554432);
  u16* nf2   = (u16*)RN;

  float* logits = (float*)d_out;
  float* h1o = logits + (size_t)NN * 8;
  float* c1o = h1o + (size_t)NN * 256;

  // 1) convert fp32 -> bf16 (obs, h0, weights)
  ConvArgs ca;
  const float* ss[13] = {obs, h0, w1a, w1b, wih, whh, w1, we, we2, wn, wn2, wr, wr2};
  u16* dd[13] = {obs_b, h0_b, w1a_b, w1b_b, wih_b, whh_b, w1_b, we_b, we2_b, wn_b, wn2_b, wr_b, wr2_b};
  int nn[13] = {NN*256, NN*256, 512*256, 256*512, 1024*256, 1024*256, 128*256,
                256*256, 128*256, 256*256, 128*256, 256*128, 8*256};
  for (int i = 0; i < 13; ++i){ ca.s[i]=ss[i]; ca.d[i]=dd[i]; ca.n4[i]=nn[i]/4; }
  ca.cnt = 13;
  convert_kernel<<<2048, 256, 0, stream>>>(ca);

  // 2) y1 = relu(obs @ w1a^T + b1a)   [N,512]
  gemm_kernel<1><<<dim3(NN/64, 8), 256, 0, stream>>>(obs_b, 256, w1a_b, 256, b1a, y1, 512);
  // 3) x = y1 @ w1b^T + b1b           [N,256]
  gemm_kernel<0><<<dim3(NN/64, 4), 256, 0, stream>>>(y1, 512, w1b_b, 512, b1b, x_b, 256);
  // 4) gates + LSTM fused -> h1, c1 (fp32 out), rb = relu(h1) bf16
  gates_lstm_kernel<<<dim3(NN/64, 4), 256, 0, stream>>>(
      x_b, h0_b, wih_b, whh_b, bih, bhh, c0, h1o, c1o, rb);
  // 5) nf = rb @ w1^T + b1 -> ninp cols 0..127 (ldc=256)
  gemm_kernel<0><<<dim3(NN/64, 2), 256, 0, stream>>>(rb, 256, w1_b, 256, b1, ninp, 256);
  // 6) agg = segment_sum(edge MLP, dst)
  hipMemsetAsync(agg, 0, (size_t)NN * 128 * 4, stream);
  edge_kernel<<<NE/64, 256, 0, stream>>>(ninp, src, dst, we_b, be, we2_b, be2, agg);
  // 7) agg -> bf16 into ninp cols 128..255
  aggconv_kernel<<<NN*32/256, 256, 0, stream>>>(agg, ninp);
  // 8) hidn = relu(ninp @ wn^T + bn)  [N,256]
  gemm_kernel<1><<<dim3(NN/64, 4), 256, 0, stream>>>(ninp, 256, wn_b, 256, bn, hidn, 256);
  // 9) nf2 = hidn @ wn2^T + bn2       [N,128]
  gemm_kernel<0><<<dim3(NN/64, 2), 256, 0, stream>>>(hidn, 256, wn2_b, 256, bn2, nf2, 128);
  // 10) rh = relu(nf2 @ wr^T + br)    [N,256]
  gemm_kernel<1><<<dim3(NN/64, 4), 256, 0, stream>>>(nf2, 128, wr_b, 128, br, rh, 256);
  // 11) logits = rh @ wr2^T + br2     [N,8] fp32
  logits_kernel<<<NN/32, 256, 0, stream>>>(rh, wr2_b, br2, logits);
}

// Round 3
// 876.804 us; speedup vs baseline: 1.2215x; 1.2215x over previous
//
#include <hip/hip_runtime.h>
#include <cstdint>
#include <cstddef>

// ---------------------------------------------------------------------------
// OppoModelNet: GNN forward
//   encoder (256->512->256) -> LSTM step (256) -> nf (128)
//   edge MLP via linear split: P=nf@we_L^T, Q=nf@we_R^T+be,
//     Hsum[n] = sum_{e:dst=n} relu(P[src_e]+Q[n])   (counting-sorted, no atomics)
//     agg = Hsum@we2^T + deg*be2
//   node MLP (256->256->128) -> readout (128->256->8)
// All GEMMs: bf16 MFMA 16x16x32, fp32 accumulate.
// ---------------------------------------------------------------------------

#define NN 65536      // nodes
#define NE 524288     // edges

typedef __bf16 bf16x8 __attribute__((ext_vector_type(8)));
typedef float  f32x4  __attribute__((ext_vector_type(4)));

__device__ __forceinline__ float bf2f(unsigned short u){
  union { unsigned int i; float f; } v; v.i = ((unsigned int)u) << 16; return v.f;
}
__device__ __forceinline__ unsigned short f2b(float f){
  union { float f; unsigned int i; } v; v.f = f;
  unsigned int r = v.i + 0x7FFFu + ((v.i >> 16) & 1u);
  return (unsigned short)(r >> 16);
}
__device__ __forceinline__ float sigm(float x){ return 1.f/(1.f+__expf(-x)); }

// ---------------------------------------------------------------------------
// batched fp32 -> bf16 conversion
// ---------------------------------------------------------------------------
struct ConvArgs {
  const float* s[14];
  unsigned short* d[14];
  int n4[14];
  int cnt;
};

__global__ __launch_bounds__(256) void convert_kernel(ConvArgs a){
  int stride = gridDim.x * blockDim.x;
  int gid = blockIdx.x * blockDim.x + threadIdx.x;
  for (int seg = 0; seg < a.cnt; ++seg){
    const float4* s = (const float4*)a.s[seg];
    ushort4* d = (ushort4*)a.d[seg];
    int n4 = a.n4[seg];
    for (int i = gid; i < n4; i += stride){
      float4 v = s[i];
      ushort4 o; o.x=f2b(v.x); o.y=f2b(v.y); o.z=f2b(v.z); o.w=f2b(v.w);
      d[i] = o;
    }
  }
}

// ---------------------------------------------------------------------------
// generic bf16 GEMM: C[M,Nc] = act(A[M,K] @ B[Nc,K]^T + biasmode), bf16 out
// tile 64x64, BK=32, 256 threads (4 waves m-split), grid (M/64, Nc/64)
// RSCALE: bias[col] * (float)rs[row]   (deg-scaled bias for agg GEMM)
// ---------------------------------------------------------------------------
template<int ACT, int RSCALE>
__global__ __launch_bounds__(256) void gemm_kernel(
    const unsigned short* __restrict__ A, int lda,
    const unsigned short* __restrict__ B, int ldb, int K,
    const float* __restrict__ bias,
    const int* __restrict__ rs,
    unsigned short* __restrict__ C, int ldc)
{
  __shared__ alignas(16) unsigned short As[2048];
  __shared__ alignas(16) unsigned short Bs[2048];
  int t = threadIdx.x, wave = t >> 6, lane = t & 63;
  int m0 = blockIdx.x * 64, n0 = blockIdx.y * 64;

  f32x4 acc[4] = {};
  int row = t >> 2, chunk = t & 3;
  int sidx = ((row >> 4) << 9) + (chunk << 7) + ((row & 15) << 3);
  const unsigned short* Ap = A + (size_t)(m0 + row) * lda + chunk * 8;
  const unsigned short* Bp = B + (size_t)(n0 + row) * ldb + chunk * 8;

  for (int kt = 0; kt < K; kt += 32){
    __syncthreads();
    *(uint4*)&As[sidx] = *(const uint4*)(Ap + kt);
    *(uint4*)&Bs[sidx] = *(const uint4*)(Bp + kt);
    __syncthreads();
    bf16x8 a = *(const bf16x8*)&As[(wave << 9) + ((lane >> 4) << 7) + ((lane & 15) << 3)];
#pragma unroll
    for (int j = 0; j < 4; ++j){
      bf16x8 b = *(const bf16x8*)&Bs[(j << 9) + ((lane >> 4) << 7) + ((lane & 15) << 3)];
      acc[j] = __builtin_amdgcn_mfma_f32_16x16x32_bf16(a, b, acc[j], 0, 0, 0);
    }
  }

  int coll = lane & 15, rq = lane >> 4;
#pragma unroll
  for (int j = 0; j < 4; ++j){
    int col = n0 + j * 16 + coll;
    float bv = bias[col];
#pragma unroll
    for (int r = 0; r < 4; ++r){
      int rrow = m0 + wave * 16 + rq * 4 + r;
      float scale = RSCALE ? (float)rs[rrow] : 1.0f;
      float v = acc[j][r] + bv * scale;
      if (ACT) v = fmaxf(v, 0.f);
      C[(size_t)rrow * ldc + col] = f2b(v);
    }
  }
}

// ---------------------------------------------------------------------------
// gates = [x|h0] @ [w_ih|w_hh]^T + b ; LSTM elementwise fused in registers.
// ---------------------------------------------------------------------------
__global__ __launch_bounds__(256) void gates_lstm_kernel(
    const unsigned short* __restrict__ Xb,   // [N,256] bf16
    const unsigned short* __restrict__ H0b,  // [N,256] bf16
    const unsigned short* __restrict__ Wih,  // [1024][256] bf16
    const unsigned short* __restrict__ Whh,  // [1024][256] bf16
    const float* __restrict__ b_ih, const float* __restrict__ b_hh,
    const float* __restrict__ c0,            // [N,256] fp32
    float* __restrict__ h1o, float* __restrict__ c1o,  // fp32 outputs
    unsigned short* __restrict__ rb)         // relu(h1) bf16 [N,256]
{
  __shared__ alignas(16) unsigned short As[2048];
  __shared__ alignas(16) unsigned short Bs[4][2048];
  int t = threadIdx.x, wave = t >> 6, lane = t & 63;
  int m0 = blockIdx.x * 64, cb = blockIdx.y * 64;

  f32x4 acc[4][4] = {};
  int row = t >> 2, chunk = t & 3;
  int sidx = ((row >> 4) << 9) + (chunk << 7) + ((row & 15) << 3);

  for (int kt = 0; kt < 512; kt += 32){
    const unsigned short* Ap = (kt < 256)
        ? (Xb  + (size_t)(m0 + row) * 256 + kt)
        : (H0b + (size_t)(m0 + row) * 256 + (kt - 256));
    __syncthreads();
    *(uint4*)&As[sidx] = *(const uint4*)(Ap + chunk * 8);
#pragma unroll
    for (int g = 0; g < 4; ++g){
      const unsigned short* Wp = (kt < 256)
          ? (Wih + (size_t)(g * 256 + cb + row) * 256 + kt)
          : (Whh + (size_t)(g * 256 + cb + row) * 256 + (kt - 256));
      *(uint4*)&Bs[g][sidx] = *(const uint4*)(Wp + chunk * 8);
    }
    __syncthreads();
    bf16x8 a = *(const bf16x8*)&As[(wave << 9) + ((lane >> 4) << 7) + ((lane & 15) << 3)];
#pragma unroll
    for (int g = 0; g < 4; ++g){
#pragma unroll
      for (int j = 0; j < 4; ++j){
        bf16x8 b = *(const bf16x8*)&Bs[g][(j << 9) + ((lane >> 4) << 7) + ((lane & 15) << 3)];
        acc[g][j] = __builtin_amdgcn_mfma_f32_16x16x32_bf16(a, b, acc[g][j], 0, 0, 0);
      }
    }
  }

  int coll = lane & 15, rq = lane >> 4;
#pragma unroll
  for (int j = 0; j < 4; ++j){
    int col = cb + j * 16 + coll;
    float bi  = b_ih[col]       + b_hh[col];
    float bff = b_ih[256 + col] + b_hh[256 + col];
    float bg  = b_ih[512 + col] + b_hh[512 + col];
    float bo  = b_ih[768 + col] + b_hh[768 + col];
#pragma unroll
    for (int r = 0; r < 4; ++r){
      int node = m0 + wave * 16 + rq * 4 + r;
      size_t off = (size_t)node * 256 + col;
      float iv = sigm(acc[0][j][r] + bi);
      float fv = sigm(acc[1][j][r] + bff);
      float gv = tanhf(acc[2][j][r] + bg);
      float ov = sigm(acc[3][j][r] + bo);
      float cv = fv * c0[off] + iv * gv;
      float hv = ov * tanhf(cv);
      h1o[off] = hv;
      c1o[off] = cv;
      rb[off] = f2b(fmaxf(hv, 0.f));
    }
  }
}

// ---------------------------------------------------------------------------
// counting sort by dst: hist -> scan -> scatter
// ---------------------------------------------------------------------------
__global__ __launch_bounds__(256) void hist_kernel(
    const int* __restrict__ dst, int* __restrict__ hist)
{
  int e = blockIdx.x * 256 + threadIdx.x;
  atomicAdd(&hist[dst[e]], 1);
}

__global__ __launch_bounds__(256) void scan1_kernel(
    const int* __restrict__ hist, int* __restrict__ offs, int* __restrict__ bsum)
{
  __shared__ int s[256];
  int b = blockIdx.x, t = threadIdx.x;
  int v = hist[b * 256 + t];
  s[t] = v; __syncthreads();
  for (int d = 1; d < 256; d <<= 1){
    int x = (t >= d) ? s[t - d] : 0;
    __syncthreads();
    s[t] += x;
    __syncthreads();
  }
  offs[b * 256 + t] = s[t] - v;
  if (t == 255) bsum[b] = s[255];
}

__global__ __launch_bounds__(256) void scan2_kernel(int* __restrict__ bsum){
  __shared__ int s[256];
  int t = threadIdx.x;
  int v = bsum[t];
  s[t] = v; __syncthreads();
  for (int d = 1; d < 256; d <<= 1){
    int x = (t >= d) ? s[t - d] : 0;
    __syncthreads();
    s[t] += x;
    __syncthreads();
  }
  bsum[t] = s[t] - v;
}

__global__ __launch_bounds__(256) void scan3_kernel(
    int* __restrict__ offs, const int* __restrict__ bsum, int* __restrict__ cursor)
{
  int i = blockIdx.x * 256 + threadIdx.x;
  int v = offs[i] + bsum[blockIdx.x];
  offs[i] = v;
  cursor[i] = v;
}

__global__ __launch_bounds__(256) void scatter_kernel(
    const int* __restrict__ src, const int* __restrict__ dst,
    int* __restrict__ cursor, int* __restrict__ sorted_src)
{
  int e = blockIdx.x * 256 + threadIdx.x;
  int d = dst[e];
  int pos = atomicAdd(&cursor[d], 1);
  sorted_src[pos] = src[e];
}

// ---------------------------------------------------------------------------
// per-node edge aggregation: Hsum[n] = sum_{e in edges(n)} relu(P[src_e]+Q[n])
// one wave per node, 4 dims/lane. No atomics; src rows graph-local (L2-hot).
// ---------------------------------------------------------------------------
__global__ __launch_bounds__(256) void edge_agg_kernel(
    const unsigned short* __restrict__ P,    // [N,256] bf16
    const unsigned short* __restrict__ Q,    // [N,256] bf16 (bias folded in)
    const int* __restrict__ sorted_src,
    const int* __restrict__ offs,
    const int* __restrict__ cnt,
    unsigned short* __restrict__ Hsum)       // [N,256] bf16
{
  int t = threadIdx.x;
  int n = (blockIdx.x << 2) + (t >> 6);
  int lane = t & 63;
  int d0 = lane * 4;
  int off = offs[n], c = cnt[n];
  ushort4 qv = *(const ushort4*)&Q[(size_t)n * 256 + d0];
  float q0 = bf2f(qv.x), q1 = bf2f(qv.y), q2 = bf2f(qv.z), q3 = bf2f(qv.w);
  float a0 = 0.f, a1 = 0.f, a2 = 0.f, a3 = 0.f;
  for (int i = 0; i < c; ++i){
    int s = sorted_src[off + i];
    ushort4 pv = *(const ushort4*)&P[(size_t)s * 256 + d0];
    a0 += fmaxf(bf2f(pv.x) + q0, 0.f);
    a1 += fmaxf(bf2f(pv.y) + q1, 0.f);
    a2 += fmaxf(bf2f(pv.z) + q2, 0.f);
    a3 += fmaxf(bf2f(pv.w) + q3, 0.f);
  }
  ushort4 o; o.x = f2b(a0); o.y = f2b(a1); o.z = f2b(a2); o.w = f2b(a3);
  *(ushort4*)&Hsum[(size_t)n * 256 + d0] = o;
}

// ---------------------------------------------------------------------------
// readout layer 2: logits[N,8] = rh[N,256] @ wr2[8,256]^T + br2  (fp32 out)
// ---------------------------------------------------------------------------
__global__ __launch_bounds__(256) void logits_kernel(
    const unsigned short* __restrict__ rh,
    const unsigned short* __restrict__ wr2b,
    const float* __restrict__ br2,
    float* __restrict__ out)
{
  __shared__ alignas(16) unsigned short W[2048];
  int t = threadIdx.x;
  *(uint4*)&W[t * 8] = *(const uint4*)&wr2b[t * 8];
  __syncthreads();
  int node = blockIdx.x * 32 + (t >> 3);
  int o = t & 7;
  const unsigned short* r = rh + (size_t)node * 256;
  float s = br2[o];
#pragma unroll
  for (int k = 0; k < 256; k += 8){
    uint4 av = *(const uint4*)&r[k];
    const unsigned short* ap = (const unsigned short*)&av;
#pragma unroll
    for (int i = 0; i < 8; ++i) s += bf2f(ap[i]) * bf2f(W[o * 256 + k + i]);
  }
  out[(size_t)node * 8 + o] = s;
}

// ---------------------------------------------------------------------------
extern "C" void kernel_launch(void* const* d_in, const int* in_sizes, int n_in,
                              void* d_out, int out_size, void* d_ws, size_t ws_size,
                              hipStream_t stream)
{
  (void)in_sizes; (void)n_in; (void)out_size; (void)ws_size;
  const float* obs = (const float*)d_in[0];
  const float* h0  = (const float*)d_in[1];
  const float* c0  = (const float*)d_in[2];
  const int*   src = (const int*)d_in[3];
  const int*   dst = (const int*)d_in[4];
  const float* w1a = (const float*)d_in[5];
  const float* b1a = (const float*)d_in[6];
  const float* w1b = (const float*)d_in[7];
  const float* b1b = (const float*)d_in[8];
  const float* wih = (const float*)d_in[9];
  const float* bih = (const float*)d_in[10];
  const float* whh = (const float*)d_in[11];
  const float* bhh = (const float*)d_in[12];
  const float* w1  = (const float*)d_in[13];
  const float* b1  = (const float*)d_in[14];
  const float* we  = (const float*)d_in[15];
  const float* be  = (const float*)d_in[16];
  const float* we2 = (const float*)d_in[17];
  const float* be2 = (const float*)d_in[18];
  const float* wn  = (const float*)d_in[19];
  const float* bn  = (const float*)d_in[20];
  const float* wn2 = (const float*)d_in[21];
  const float* bn2 = (const float*)d_in[22];
  const float* wr  = (const float*)d_in[23];
  const float* br  = (const float*)d_in[24];
  const float* wr2 = (const float*)d_in[25];
  const float* br2 = (const float*)d_in[26];

  char* ws = (char*)d_ws;
  typedef unsigned short u16;
  // bf16 weight copies + sort scratch
  u16* w1a_b = (u16*)(ws + 0);
  u16* w1b_b = (u16*)(ws + 262144);
  u16* wih_b = (u16*)(ws + 524288);
  u16* whh_b = (u16*)(ws + 1048576);
  u16* w1_b  = (u16*)(ws + 1572864);
  u16* we_b  = (u16*)(ws + 1638400);
  u16* we2_b = (u16*)(ws + 1769472);
  u16* wn_b  = (u16*)(ws + 1835008);
  u16* wn2_b = (u16*)(ws + 1966080);
  u16* wr_b  = (u16*)(ws + 2031616);
  u16* wr2_b = (u16*)(ws + 2097152);
  float* zbias = (float*)(ws + 2101248);        // 512 fp32 zeros
  int* hist    = (int*)(ws + 2103296);          // [65536] = deg
  int* offs    = (int*)(ws + 2365440);          // [65536]
  int* cursor  = (int*)(ws + 2627584);          // [65536]
  int* bsum    = (int*)(ws + 2889728);          // [256]
  int* ssrc    = (int*)(ws + 2890752);          // sorted_src [524288]

  // aliased activation regions
  char* RA = ws + 5242880;    // 33.5MB: obs_b -> x_b -> P -> nf2
  char* RB = ws + 38797312;   // 33.5MB: h0_b -> Hsum -> hidn -> rh
  char* RY = ws + 72351744;   // 67MB:   y1 -> [rb->Q | ninp]

  u16* obs_b = (u16*)RA;
  u16* x_b   = (u16*)RA;
  u16* P     = (u16*)RA;
  u16* nf2   = (u16*)RA;
  u16* h0_b  = (u16*)RB;
  u16* Hsum  = (u16*)RB;
  u16* hidn  = (u16*)RB;
  u16* rh    = (u16*)RB;
  u16* y1    = (u16*)RY;
  u16* rb    = (u16*)RY;
  u16* Q     = (u16*)RY;
  u16* ninp  = (u16*)(RY + 33554432);

  float* logits = (float*)d_out;
  float* h1o = logits + (size_t)NN * 8;
  float* c1o = h1o + (size_t)NN * 256;

  // 0) zero-init scratch
  (void)hipMemsetAsync(zbias, 0, 2048, stream);
  (void)hipMemsetAsync(hist, 0, 65536 * 4, stream);

  // 1) convert fp32 -> bf16
  ConvArgs ca;
  const float* ss[13] = {obs, h0, w1a, w1b, wih, whh, w1, we, we2, wn, wn2, wr, wr2};
  u16* dd[13] = {obs_b, h0_b, w1a_b, w1b_b, wih_b, whh_b, w1_b, we_b, we2_b, wn_b, wn2_b, wr_b, wr2_b};
  int nn[13] = {NN*256, NN*256, 512*256, 256*512, 1024*256, 1024*256, 128*256,
                256*256, 128*256, 256*256, 128*256, 256*128, 8*256};
  for (int i = 0; i < 13; ++i){ ca.s[i]=ss[i]; ca.d[i]=dd[i]; ca.n4[i]=nn[i]/4; }
  ca.cnt = 13;
  convert_kernel<<<2048, 256, 0, stream>>>(ca);

  // 2) counting sort of edges by dst (independent of GEMM chain)
  hist_kernel<<<NE/256, 256, 0, stream>>>(dst, hist);
  scan1_kernel<<<256, 256, 0, stream>>>(hist, offs, bsum);
  scan2_kernel<<<1, 256, 0, stream>>>(bsum);
  scan3_kernel<<<256, 256, 0, stream>>>(offs, bsum, cursor);
  scatter_kernel<<<NE/256, 256, 0, stream>>>(src, dst, cursor, ssrc);

  // 3) y1 = relu(obs @ w1a^T + b1a)   [N,512]
  gemm_kernel<1,0><<<dim3(NN/64, 8), 256, 0, stream>>>(obs_b, 256, w1a_b, 256, 256, b1a, nullptr, y1, 512);
  // 4) x = y1 @ w1b^T + b1b           [N,256]
  gemm_kernel<0,0><<<dim3(NN/64, 4), 256, 0, stream>>>(y1, 512, w1b_b, 512, 512, b1b, nullptr, x_b, 256);
  // 5) gates + LSTM fused -> h1, c1 (fp32 out), rb = relu(h1) bf16
  gates_lstm_kernel<<<dim3(NN/64, 4), 256, 0, stream>>>(
      x_b, h0_b, wih_b, whh_b, bih, bhh, c0, h1o, c1o, rb);
  // 6) nf = rb @ w1^T + b1 -> ninp cols 0..127 (ldc=256)
  gemm_kernel<0,0><<<dim3(NN/64, 2), 256, 0, stream>>>(rb, 256, w1_b, 256, 256, b1, nullptr, ninp, 256);
  // 7) P = nf @ we_L^T (zero bias)    [N,256], K=128
  gemm_kernel<0,0><<<dim3(NN/64, 4), 256, 0, stream>>>(ninp, 256, we_b, 256, 128, zbias, nullptr, P, 256);
  // 8) Q = nf @ we_R^T + be           [N,256], K=128
  gemm_kernel<0,0><<<dim3(NN/64, 4), 256, 0, stream>>>(ninp, 256, we_b + 128, 256, 128, be, nullptr, Q, 256);
  // 9) Hsum[n] = sum over edges relu(P[src]+Q[n])
  edge_agg_kernel<<<NN/4, 256, 0, stream>>>(P, Q, ssrc, offs, hist, Hsum);
  // 10) agg = Hsum @ we2^T + deg*be2 -> ninp cols 128..255
  gemm_kernel<0,1><<<dim3(NN/64, 2), 256, 0, stream>>>(Hsum, 256, we2_b, 256, 256, be2, hist, ninp + 128, 256);
  // 11) hidn = relu(ninp @ wn^T + bn)  [N,256]
  gemm_kernel<1,0><<<dim3(NN/64, 4), 256, 0, stream>>>(ninp, 256, wn_b, 256, 256, bn, nullptr, hidn, 256);
  // 12) nf2 = hidn @ wn2^T + bn2       [N,128]
  gemm_kernel<0,0><<<dim3(NN/64, 2), 256, 0, stream>>>(hidn, 256, wn2_b, 256, 256, bn2, nullptr, nf2, 128);
  // 13) rh = relu(nf2 @ wr^T + br)     [N,256]
  gemm_kernel<1,0><<<dim3(NN/64, 4), 256, 0, stream>>>(nf2, 128, wr_b, 128, 128, br, nullptr, rh, 256);
  // 14) logits = rh @ wr2^T + br2      [N,8] fp32
  logits_kernel<<<NN/32, 256, 0, stream>>>(rh, wr2_b, br2, logits);
}